// Round 2
// baseline (7920.778 us; speedup 1.0000x reference)
//
#include <hip/hip_runtime.h>
#include <math.h>

#define D_MODEL 128
#define HW      1024
#define DEPTH   4
#define NIMG    128   // B*T
#define B_      8
#define T_      16
#define LN_EPSF 1e-5f

__device__ __forceinline__ float sigmoidf_(float x) { return 1.0f / (1.0f + expf(-x)); }

// ---------------------------------------------------------------------------
// gates: z[e] = sum_d in[n,d,q] * Wi[e,d]  (e in [0,384))
//        iu = sigmoid(z_i)*tanh(z_u), og = sigmoid(z_o)
// Block = 256 threads handles 64 positions of one image; stages X tile in LDS
// (all 128 d), so writing og over `in` (in-place) is safe.
// ---------------------------------------------------------------------------
__global__ __launch_bounds__(256) void gates_kernel(
    const float* __restrict__ in, const float* __restrict__ Wi,
    float* __restrict__ iu, float* __restrict__ og)
{
    __shared__ float Xs[D_MODEL][64];
    const int n  = blockIdx.x >> 4;        // 16 q-tiles per image
    const int q0 = (blockIdx.x & 15) << 6;
    const int tid = threadIdx.x;
    const float* inb = in + (size_t)n * (D_MODEL * HW) + q0;

    for (int r = tid; r < D_MODEL * 64; r += 256) {
        int d = r >> 6, q = r & 63;
        Xs[d][q] = inb[(size_t)d * HW + q];
    }
    __syncthreads();

    const int qt = tid & 63;
    const int eg = tid >> 6;               // 0..3 (wave-uniform)
    const size_t obase = (size_t)n * (D_MODEL * HW) + q0 + qt;

    for (int ee = 0; ee < 32; ++ee) {
        const int ec = eg * 32 + ee;       // 0..127
        const float* wu = Wi + (size_t)ec * D_MODEL;
        const float* wi = Wi + (size_t)(ec + 128) * D_MODEL;
        const float* wo = Wi + (size_t)(ec + 256) * D_MODEL;
        float zu = 0.f, zi = 0.f, zo = 0.f;
        #pragma unroll 8
        for (int d = 0; d < D_MODEL; ++d) {
            const float xv = Xs[d][qt];
            zu = fmaf(xv, wu[d], zu);
            zi = fmaf(xv, wi[d], zi);
            zo = fmaf(xv, wo[d], zo);
        }
        iu[obase + (size_t)ec * HW] = sigmoidf_(zi) * tanhf(zu);
        og[obase + (size_t)ec * HW] = sigmoidf_(zo);
    }
}

// ---------------------------------------------------------------------------
// scan2d: per (n,d) 32x32 plane, compute sum of 4 directional scans of iu,
// in place. 4 planes per block (128 threads).
// ---------------------------------------------------------------------------
__global__ __launch_bounds__(128) void scan2d_kernel(
    float* __restrict__ buf, const float* __restrict__ Avec)
{
    __shared__ float L[4][32][33];
    __shared__ float S[4][32][33];
    const int pl = threadIdx.x >> 5;  // 0..3
    const int r  = threadIdx.x & 31;
    const int plane = blockIdx.x * 4 + pl;
    const int d = plane & (D_MODEL - 1);
    float* base = buf + (size_t)plane * HW;
    const float a = fminf(expf(Avec[d]), 0.999f);

    for (int k = 0; k < 32; ++k) L[pl][k][r] = base[k * 32 + r];
    __syncthreads();

    // row scans (thread owns row r): forward + backward along j
    {
        float acc[32];
        float s = 0.f;
        #pragma unroll
        for (int j = 0; j < 32; ++j) { s = fmaf(a, s, L[pl][r][j]); acc[j] = s; }
        s = 0.f;
        #pragma unroll
        for (int j = 31; j >= 0; --j) { s = fmaf(a, s, L[pl][r][j]); acc[j] += s; }
        #pragma unroll
        for (int j = 0; j < 32; ++j) S[pl][r][j] = acc[j];
    }
    __syncthreads();
    // column scans (thread owns column r): forward + backward along i
    {
        float s = 0.f;
        #pragma unroll
        for (int i = 0; i < 32; ++i) { s = fmaf(a, s, L[pl][i][r]); S[pl][i][r] += s; }
        s = 0.f;
        #pragma unroll
        for (int i = 31; i >= 0; --i) { s = fmaf(a, s, L[pl][i][r]); S[pl][i][r] += s; }
    }
    __syncthreads();
    for (int k = 0; k < 32; ++k) base[k * 32 + r] = S[pl][k][r];
}

// ---------------------------------------------------------------------------
// outgemm: out[n,e,q] = (resid ? resid[idx] : 0) + sum_d Wo[e,d]*(og*S*scale)
// Stages gated product in LDS first -> in-place over og/S safe.
// ---------------------------------------------------------------------------
__global__ __launch_bounds__(256) void outgemm_kernel(
    const float* __restrict__ S, const float* __restrict__ og,
    const float* __restrict__ Wo, const float* __restrict__ resid,
    float* __restrict__ out, float scale)
{
    __shared__ float G[D_MODEL][64];
    const int n  = blockIdx.x >> 4;
    const int q0 = (blockIdx.x & 15) << 6;
    const int tid = threadIdx.x;
    const size_t ib = (size_t)n * (D_MODEL * HW) + q0;

    for (int r = tid; r < D_MODEL * 64; r += 256) {
        int d = r >> 6, q = r & 63;
        size_t idx = ib + (size_t)d * HW + q;
        G[d][q] = og[idx] * S[idx] * scale;
    }
    __syncthreads();

    const int qt = tid & 63;
    const int eg = tid >> 6;
    for (int ee = 0; ee < 32; ++ee) {
        const int e = eg * 32 + ee;
        const float* w = Wo + (size_t)e * D_MODEL;
        float acc = 0.f;
        #pragma unroll 8
        for (int d = 0; d < D_MODEL; ++d) acc = fmaf(G[d][qt], w[d], acc);
        const size_t oidx = ib + (size_t)e * HW + qt;
        out[oidx] = (resid ? resid[oidx] : 0.f) + acc;
    }
}

// ---------------------------------------------------------------------------
// tscan: causal scan over T in place. buf layout [B,T,D,HW]. thread/(b,d,q).
// ---------------------------------------------------------------------------
__global__ __launch_bounds__(256) void tscan_kernel(
    float* __restrict__ buf, const float* __restrict__ Avec)
{
    const int idx = blockIdx.x * 256 + threadIdx.x;  // B*D*HW = 1048576
    if (idx >= B_ * D_MODEL * HW) return;
    const int q = idx & (HW - 1);
    const int rest = idx >> 10;
    const int d = rest & (D_MODEL - 1);
    const int b = rest >> 7;
    const float a = fminf(expf(Avec[d]), 0.999f);
    size_t base = (size_t)b * (T_ * D_MODEL * HW) + (size_t)d * HW + q;
    float s = 0.f;
    for (int t = 0; t < T_; ++t) {
        const size_t id2 = base + (size_t)t * (D_MODEL * HW);
        s = fmaf(a, s, buf[id2]);
        buf[id2] = s;
    }
}

// ---------------------------------------------------------------------------
// ln: LayerNorm over D per position, two-pass, in place on X.
// ---------------------------------------------------------------------------
__global__ __launch_bounds__(256) void ln_kernel(
    float* __restrict__ X, const float* __restrict__ g, const float* __restrict__ b)
{
    const int p = blockIdx.x * 256 + threadIdx.x;  // NIMG*HW = 131072
    if (p >= NIMG * HW) return;
    const int q = p & (HW - 1);
    const int n = p >> 10;
    const size_t base = (size_t)n * (D_MODEL * HW) + q;
    float sum = 0.f, sumsq = 0.f;
    for (int d = 0; d < D_MODEL; ++d) {
        const float x = X[base + (size_t)d * HW];
        sum += x; sumsq += x * x;
    }
    const float mean = sum * (1.f / D_MODEL);
    const float var  = sumsq * (1.f / D_MODEL) - mean * mean;
    const float rstd = rsqrtf(var + LN_EPSF);
    for (int d = 0; d < D_MODEL; ++d) {
        const size_t idx = base + (size_t)d * HW;
        X[idx] = (X[idx] - mean) * rstd * g[d] + b[d];
    }
}

// ---------------------------------------------------------------------------
extern "C" void kernel_launch(void* const* d_in, const int* in_sizes, int n_in,
                              void* d_out, int out_size, void* d_ws, size_t ws_size,
                              hipStream_t stream) {
    const float* tok   = (const float*)d_in[0];
    const float* s_inp = (const float*)d_in[1];
    const float* s_A   = (const float*)d_in[2];
    const float* s_out = (const float*)d_in[3];
    const float* t_inp = (const float*)d_in[4];
    const float* t_A   = (const float*)d_in[5];
    const float* t_out = (const float*)d_in[6];
    const float* ln_g  = (const float*)d_in[7];
    const float* ln_b  = (const float*)d_in[8];

    float* X = (float*)d_out;                 // running activation [B,T,D,h,w]
    float* A = (float*)d_ws;                  // 64 MB: iu / scan state
    float* Bf = A + (size_t)NIMG * D_MODEL * HW;  // 64 MB: og / xs

    const dim3 blk256(256), blk128(128);
    const int g_tiles = NIMG * 16;            // 2048

    for (int l = 0; l < DEPTH; ++l) {
        const float* xin = (l == 0) ? tok : X;
        const float* sWi = s_inp + (size_t)l * 384 * 128;
        const float* sAv = s_A   + (size_t)l * 128;
        const float* sWo = s_out + (size_t)l * 128 * 128;
        const float* tWi = t_inp + (size_t)l * 384 * 128;
        const float* tAv = t_A   + (size_t)l * 128;
        const float* tWo = t_out + (size_t)l * 128 * 128;

        // spatial stage
        gates_kernel<<<g_tiles, blk256, 0, stream>>>(xin, sWi, A, Bf);
        scan2d_kernel<<<(NIMG * D_MODEL) / 4, blk128, 0, stream>>>(A, sAv);
        outgemm_kernel<<<g_tiles, blk256, 0, stream>>>(A, Bf, sWo, nullptr, Bf, 0.25f);
        // temporal stage (Bf holds xs); og written in place over xs
        gates_kernel<<<g_tiles, blk256, 0, stream>>>(Bf, tWi, A, Bf);
        tscan_kernel<<<(B_ * D_MODEL * HW) / 256, blk256, 0, stream>>>(A, tAv);
        outgemm_kernel<<<g_tiles, blk256, 0, stream>>>(A, Bf, tWo, xin, X, 1.0f);
    }
    ln_kernel<<<(NIMG * HW) / 256, blk256, 0, stream>>>(X, ln_g, ln_b);
}

// Round 3
// 750.743 us; speedup vs baseline: 10.5506x; 10.5506x over previous
//
#include <hip/hip_runtime.h>
#include <hip/hip_bf16.h>
#include <math.h>

#define D_MODEL 128
#define HW      1024
#define DEPTH   4
#define NIMG    128   // B*T
#define B_      8
#define T_      16
#define LN_EPSF 1e-5f

typedef short  short8 __attribute__((ext_vector_type(8)));
typedef float  f32x4  __attribute__((ext_vector_type(4)));

__device__ __forceinline__ float sig_(float x) { return 1.0f / (1.0f + __expf(-x)); }
__device__ __forceinline__ float tanh_(float x) { return 2.0f * sig_(2.0f * x) - 1.0f; }

__device__ __forceinline__ ushort f2b(float f) {
    __hip_bfloat16 h = __float2bfloat16(f);
    return *reinterpret_cast<ushort*>(&h);
}
__device__ __forceinline__ float b2f(ushort u) {
    __hip_bfloat16 h = *reinterpret_cast<__hip_bfloat16*>(&u);
    return __bfloat162float(h);
}

// ---------------------------------------------------------------------------
// wconv: fp32 -> bf16 weight pre-conversion
// ---------------------------------------------------------------------------
__global__ __launch_bounds__(256) void wconv_kernel(
    const float* __restrict__ src, ushort* __restrict__ dst, int n)
{
    int i = blockIdx.x * 256 + threadIdx.x;
    if (i < n) dst[i] = f2b(src[i]);
}

// ---------------------------------------------------------------------------
// gates MFMA: z[e,q] = sum_d Wi[e,d] * X[d,q], e in [0,384)
// iu = sig(z_i)*tanh(z_u) -> iu buf (bf16); og = sig(z_o) -> og buf (bf16)
// Block: 256 thr (4 waves), one (image, 64-pos) tile. Wave w owns channels
// [w*32, w*32+32) for ALL THREE gates -> fuse nonlinearity in-register.
// In-place safe (og may alias in): X-tile fully staged to LDS before writes.
// ---------------------------------------------------------------------------
template <typename InT>
__global__ __launch_bounds__(256, 2) void gates_mfma_kernel(
    const InT* __restrict__ in, const ushort* __restrict__ Wi,
    ushort* __restrict__ iu, ushort* __restrict__ og)
{
    __shared__ ushort Xs[64][136];   // [q][d], pad->272B rows (16B-aligned)
    const int n   = blockIdx.x >> 4;
    const int q0  = (blockIdx.x & 15) << 6;
    const int tid = threadIdx.x;
    const size_t nbase = (size_t)n * (D_MODEL * HW);

    // stage: transpose X[d][q] -> Xs[q][d] as bf16, b128 LDS writes
    {
        const InT* inb = in + nbase + q0;
        const int q   = tid & 63;
        const int dh0 = tid >> 6;
        for (int it = 0; it < 4; ++it) {
            const int dh = dh0 + it * 4;        // 8-wide d-block, 0..15
            short8 pk;
            #pragma unroll
            for (int j = 0; j < 8; ++j) {
                float v;
                if constexpr (sizeof(InT) == 4) v = ((const float*)inb)[(size_t)(dh * 8 + j) * HW + q];
                else                            v = b2f(((const ushort*)inb)[(size_t)(dh * 8 + j) * HW + q]);
                pk[j] = (short)f2b(v);
            }
            *reinterpret_cast<short8*>(&Xs[q][dh * 8]) = pk;
        }
    }
    __syncthreads();

    const int lane = tid & 63;
    const int wv   = tid >> 6;
    const int grp  = lane >> 4;
    const int lrow = lane & 15;
    const int ch0  = wv * 32;

    f32x4 aU[2][4], aI[2][4], aO[2][4];
    #pragma unroll
    for (int rt = 0; rt < 2; ++rt)
        #pragma unroll
        for (int ct = 0; ct < 4; ++ct) { aU[rt][ct] = (f32x4)0.f; aI[rt][ct] = (f32x4)0.f; aO[rt][ct] = (f32x4)0.f; }

    #pragma unroll
    for (int kk = 0; kk < 4; ++kk) {
        const int kb = kk * 32 + grp * 8;
        short8 wu[2], wi[2], wo[2], xb[4];
        #pragma unroll
        for (int rt = 0; rt < 2; ++rt) {
            const int e = ch0 + rt * 16 + lrow;
            wu[rt] = *reinterpret_cast<const short8*>(Wi + (size_t)e * D_MODEL + kb);
            wi[rt] = *reinterpret_cast<const short8*>(Wi + (size_t)(e + 128) * D_MODEL + kb);
            wo[rt] = *reinterpret_cast<const short8*>(Wi + (size_t)(e + 256) * D_MODEL + kb);
        }
        #pragma unroll
        for (int ct = 0; ct < 4; ++ct)
            xb[ct] = *reinterpret_cast<const short8*>(&Xs[ct * 16 + lrow][kb]);
        #pragma unroll
        for (int rt = 0; rt < 2; ++rt)
            #pragma unroll
            for (int ct = 0; ct < 4; ++ct) {
                aU[rt][ct] = __builtin_amdgcn_mfma_f32_16x16x32_bf16(wu[rt], xb[ct], aU[rt][ct], 0, 0, 0);
                aI[rt][ct] = __builtin_amdgcn_mfma_f32_16x16x32_bf16(wi[rt], xb[ct], aI[rt][ct], 0, 0, 0);
                aO[rt][ct] = __builtin_amdgcn_mfma_f32_16x16x32_bf16(wo[rt], xb[ct], aO[rt][ct], 0, 0, 0);
            }
    }

    // epilogue: C/D layout col=lane&15 (q), row=(lane>>4)*4+i (e)
    #pragma unroll
    for (int rt = 0; rt < 2; ++rt)
        #pragma unroll
        for (int ct = 0; ct < 4; ++ct)
            #pragma unroll
            for (int i = 0; i < 4; ++i) {
                const int c = ch0 + rt * 16 + grp * 4 + i;
                const int q = q0 + ct * 16 + lrow;
                const size_t idx = nbase + (size_t)c * HW + q;
                iu[idx] = f2b(sig_(aI[rt][ct][i]) * tanh_(aU[rt][ct][i]));
                og[idx] = f2b(sig_(aO[rt][ct][i]));
            }
}

// ---------------------------------------------------------------------------
// outgemm MFMA: out[e,q] = (RES? resid : 0) + sum_d Wo[e,d]*(og*S*scale)[d,q]
// Gated product fused into LDS staging; in-place over og/S safe.
// ---------------------------------------------------------------------------
template <typename OutT, bool RES>
__global__ __launch_bounds__(256, 2) void outgemm_mfma_kernel(
    const ushort* __restrict__ S, const ushort* __restrict__ og,
    const ushort* __restrict__ Wo, const float* __restrict__ resid,
    OutT* __restrict__ out, float scale)
{
    __shared__ ushort Gs[64][136];
    const int n   = blockIdx.x >> 4;
    const int q0  = (blockIdx.x & 15) << 6;
    const int tid = threadIdx.x;
    const size_t nbase = (size_t)n * (D_MODEL * HW);

    {
        const ushort* Sb = S  + nbase + q0;
        const ushort* Ob = og + nbase + q0;
        const int q   = tid & 63;
        const int dh0 = tid >> 6;
        for (int it = 0; it < 4; ++it) {
            const int dh = dh0 + it * 4;
            short8 pk;
            #pragma unroll
            for (int j = 0; j < 8; ++j) {
                const size_t o = (size_t)(dh * 8 + j) * HW + q;
                pk[j] = (short)f2b(b2f(Ob[o]) * b2f(Sb[o]) * scale);
            }
            *reinterpret_cast<short8*>(&Gs[q][dh * 8]) = pk;
        }
    }
    __syncthreads();

    const int lane = tid & 63;
    const int wv   = tid >> 6;
    const int grp  = lane >> 4;
    const int lrow = lane & 15;
    const int ch0  = wv * 32;

    f32x4 acc[2][4];
    #pragma unroll
    for (int rt = 0; rt < 2; ++rt)
        #pragma unroll
        for (int ct = 0; ct < 4; ++ct) acc[rt][ct] = (f32x4)0.f;

    #pragma unroll
    for (int kk = 0; kk < 4; ++kk) {
        const int kb = kk * 32 + grp * 8;
        short8 wf[2], xb[4];
        #pragma unroll
        for (int rt = 0; rt < 2; ++rt)
            wf[rt] = *reinterpret_cast<const short8*>(Wo + (size_t)(ch0 + rt * 16 + lrow) * D_MODEL + kb);
        #pragma unroll
        for (int ct = 0; ct < 4; ++ct)
            xb[ct] = *reinterpret_cast<const short8*>(&Gs[ct * 16 + lrow][kb]);
        #pragma unroll
        for (int rt = 0; rt < 2; ++rt)
            #pragma unroll
            for (int ct = 0; ct < 4; ++ct)
                acc[rt][ct] = __builtin_amdgcn_mfma_f32_16x16x32_bf16(wf[rt], xb[ct], acc[rt][ct], 0, 0, 0);
    }

    #pragma unroll
    for (int rt = 0; rt < 2; ++rt)
        #pragma unroll
        for (int ct = 0; ct < 4; ++ct)
            #pragma unroll
            for (int i = 0; i < 4; ++i) {
                const int e = ch0 + rt * 16 + grp * 4 + i;
                const int q = q0 + ct * 16 + lrow;
                const size_t idx = nbase + (size_t)e * HW + q;
                float v = acc[rt][ct][i];
                if constexpr (RES) v += resid[idx];
                if constexpr (sizeof(OutT) == 2) out[idx] = (OutT)f2b(v);
                else                             out[idx] = (OutT)v;
            }
}

// ---------------------------------------------------------------------------
// scan2d: per (n,d) 32x32 plane, sum of 4 directional scans, in place (bf16).
// ---------------------------------------------------------------------------
__global__ __launch_bounds__(128) void scan2d_kernel(
    ushort* __restrict__ buf, const float* __restrict__ Avec)
{
    __shared__ float L[4][32][33];
    __shared__ float S[4][32][33];
    const int pl = threadIdx.x >> 5;
    const int r  = threadIdx.x & 31;
    const int plane = blockIdx.x * 4 + pl;
    const int d = plane & (D_MODEL - 1);
    ushort* base = buf + (size_t)plane * HW;
    const float a = fminf(__expf(Avec[d]), 0.999f);

    for (int k = 0; k < 32; ++k) L[pl][k][r] = b2f(base[k * 32 + r]);
    __syncthreads();

    {
        float acc[32];
        float s = 0.f;
        #pragma unroll
        for (int j = 0; j < 32; ++j) { s = fmaf(a, s, L[pl][r][j]); acc[j] = s; }
        s = 0.f;
        #pragma unroll
        for (int j = 31; j >= 0; --j) { s = fmaf(a, s, L[pl][r][j]); acc[j] += s; }
        #pragma unroll
        for (int j = 0; j < 32; ++j) S[pl][r][j] = acc[j];
    }
    __syncthreads();
    {
        float s = 0.f;
        #pragma unroll
        for (int i = 0; i < 32; ++i) { s = fmaf(a, s, L[pl][i][r]); S[pl][i][r] += s; }
        s = 0.f;
        #pragma unroll
        for (int i = 31; i >= 0; --i) { s = fmaf(a, s, L[pl][i][r]); S[pl][i][r] += s; }
    }
    __syncthreads();
    for (int k = 0; k < 32; ++k) base[k * 32 + r] = f2b(S[pl][k][r]);
}

// ---------------------------------------------------------------------------
// tscan: causal scan over T in place (bf16 buf). thread/(b,d,q).
// ---------------------------------------------------------------------------
__global__ __launch_bounds__(256) void tscan_kernel(
    ushort* __restrict__ buf, const float* __restrict__ Avec)
{
    const int idx = blockIdx.x * 256 + threadIdx.x;
    if (idx >= B_ * D_MODEL * HW) return;
    const int q = idx & (HW - 1);
    const int rest = idx >> 10;
    const int d = rest & (D_MODEL - 1);
    const int b = rest >> 7;
    const float a = fminf(__expf(Avec[d]), 0.999f);
    size_t base = (size_t)b * (T_ * D_MODEL * HW) + (size_t)d * HW + q;
    float s = 0.f;
    for (int t = 0; t < T_; ++t) {
        const size_t id2 = base + (size_t)t * (D_MODEL * HW);
        s = fmaf(a, s, b2f(buf[id2]));
        buf[id2] = f2b(s);
    }
}

// ---------------------------------------------------------------------------
// ln: LayerNorm over D per position, two-pass, in place on X (fp32).
// ---------------------------------------------------------------------------
__global__ __launch_bounds__(256) void ln_kernel(
    float* __restrict__ X, const float* __restrict__ g, const float* __restrict__ b)
{
    const int p = blockIdx.x * 256 + threadIdx.x;
    if (p >= NIMG * HW) return;
    const int q = p & (HW - 1);
    const int n = p >> 10;
    const size_t base = (size_t)n * (D_MODEL * HW) + q;
    float sum = 0.f, sumsq = 0.f;
    for (int d = 0; d < D_MODEL; ++d) {
        const float x = X[base + (size_t)d * HW];
        sum += x; sumsq += x * x;
    }
    const float mean = sum * (1.f / D_MODEL);
    const float var  = sumsq * (1.f / D_MODEL) - mean * mean;
    const float rstd = rsqrtf(var + LN_EPSF);
    for (int d = 0; d < D_MODEL; ++d) {
        const size_t idx = base + (size_t)d * HW;
        X[idx] = (X[idx] - mean) * rstd * g[d] + b[d];
    }
}

// ---------------------------------------------------------------------------
extern "C" void kernel_launch(void* const* d_in, const int* in_sizes, int n_in,
                              void* d_out, int out_size, void* d_ws, size_t ws_size,
                              hipStream_t stream) {
    const float* tok   = (const float*)d_in[0];
    const float* s_inp = (const float*)d_in[1];
    const float* s_A   = (const float*)d_in[2];
    const float* s_out = (const float*)d_in[3];
    const float* t_inp = (const float*)d_in[4];
    const float* t_A   = (const float*)d_in[5];
    const float* t_out = (const float*)d_in[6];
    const float* ln_g  = (const float*)d_in[7];
    const float* ln_b  = (const float*)d_in[8];

    float*  X    = (float*)d_out;                    // residual stream fp32
    ushort* Abuf = (ushort*)d_ws;                    // 32MB bf16 (iu / S)
    ushort* Bbuf = Abuf + (size_t)16777216;          // 32MB bf16 (og / xs)
    ushort* Wbf  = Bbuf + (size_t)16777216;          // 1MB bf16 weights
    ushort* sWiB = Wbf;                              // 4*49152
    ushort* sWoB = Wbf + 196608;                     // 4*16384
    ushort* tWiB = Wbf + 262144;
    ushort* tWoB = Wbf + 458752;

    const dim3 blk256(256), blk128(128);

    wconv_kernel<<<768, blk256, 0, stream>>>(s_inp, sWiB, 196608);
    wconv_kernel<<<256, blk256, 0, stream>>>(s_out, sWoB, 65536);
    wconv_kernel<<<768, blk256, 0, stream>>>(t_inp, tWiB, 196608);
    wconv_kernel<<<256, blk256, 0, stream>>>(t_out, tWoB, 65536);

    for (int l = 0; l < DEPTH; ++l) {
        const float* xin = (l == 0) ? tok : X;

        // spatial stage
        gates_mfma_kernel<float><<<2048, blk256, 0, stream>>>(
            xin, sWiB + (size_t)l * 49152, Abuf, Bbuf);
        scan2d_kernel<<<4096, blk128, 0, stream>>>(Abuf, s_A + (size_t)l * 128);
        outgemm_mfma_kernel<ushort, false><<<2048, blk256, 0, stream>>>(
            Abuf, Bbuf, sWoB + (size_t)l * 16384, nullptr, Bbuf, 0.25f);

        // temporal stage (Bbuf holds xs bf16; og written in place over xs)
        gates_mfma_kernel<ushort><<<2048, blk256, 0, stream>>>(
            Bbuf, tWiB + (size_t)l * 49152, Abuf, Bbuf);
        tscan_kernel<<<4096, blk256, 0, stream>>>(Abuf, t_A + (size_t)l * 128);
        outgemm_mfma_kernel<float, true><<<2048, blk256, 0, stream>>>(
            Abuf, Bbuf, tWoB + (size_t)l * 16384, xin, X, 1.0f);
    }
    ln_kernel<<<512, blk256, 0, stream>>>(X, ln_g, ln_b);
}

// Round 5
// 707.187 us; speedup vs baseline: 11.2004x; 1.0616x over previous
//
#include <hip/hip_runtime.h>
#include <hip/hip_bf16.h>
#include <math.h>

#define D_MODEL 128
#define HW      1024
#define DEPTH   4
#define NIMG    128   // B*T
#define B_      8
#define T_      16
#define LN_EPSF 1e-5f

typedef short  s8  __attribute__((ext_vector_type(8)));
typedef ushort us4 __attribute__((ext_vector_type(4)));
typedef ushort us2 __attribute__((ext_vector_type(2)));
typedef float  f4  __attribute__((ext_vector_type(4)));

__device__ __forceinline__ float sig_(float x) { return 1.0f / (1.0f + __expf(-x)); }
__device__ __forceinline__ float tanh_(float x) { return 2.0f * sig_(2.0f * x) - 1.0f; }
__device__ __forceinline__ ushort f2b(float f) {
    __hip_bfloat16 h = __float2bfloat16(f);
    return *reinterpret_cast<ushort*>(&h);
}
__device__ __forceinline__ float b2f(ushort u) {
    __hip_bfloat16 h = *reinterpret_cast<__hip_bfloat16*>(&u);
    return __bfloat162float(h);
}

// ---------------------------------------------------------------------------
// wconv: fp32 -> bf16 weight pre-conversion
// ---------------------------------------------------------------------------
__global__ __launch_bounds__(256) void wconv_kernel(
    const float* __restrict__ src, ushort* __restrict__ dst, int n)
{
    int i = blockIdx.x * 256 + threadIdx.x;
    if (i < n) dst[i] = f2b(src[i]);
}

// ---------------------------------------------------------------------------
// 3-gate MFMA from an LDS tile Xs[q][d] (bf16), orientation X (A = activations):
// C rows = q (4 consecutive per lane -> us4 stores), cols = channels.
// Writes iu = sig(z_i)*tanh(z_u), og = sig(z_o) as bf16, vectorized.
// ---------------------------------------------------------------------------
__device__ __forceinline__ void gates_from_lds(
    const ushort (*Xs)[136], const ushort* __restrict__ Wi,
    ushort* __restrict__ iu, ushort* __restrict__ og,
    size_t nbase, int q0, int tid)
{
    const int lane = tid & 63;
    const int wv   = tid >> 6;
    const int grp  = lane >> 4;
    const int lrow = lane & 15;
    const int ch0  = wv * 32;

    f4 aU[4][2], aI[4][2], aO[4][2];
    #pragma unroll
    for (int mt = 0; mt < 4; ++mt)
        #pragma unroll
        for (int nt = 0; nt < 2; ++nt) { aU[mt][nt] = (f4)0.f; aI[mt][nt] = (f4)0.f; aO[mt][nt] = (f4)0.f; }

    #pragma unroll
    for (int kk = 0; kk < 4; ++kk) {
        const int kb = kk * 32 + grp * 8;
        s8 xa[4], wu[2], wi[2], wo[2];
        #pragma unroll
        for (int mt = 0; mt < 4; ++mt)
            xa[mt] = *reinterpret_cast<const s8*>(&Xs[mt * 16 + lrow][kb]);
        #pragma unroll
        for (int nt = 0; nt < 2; ++nt) {
            const int e = ch0 + nt * 16 + lrow;
            wu[nt] = *reinterpret_cast<const s8*>(Wi + (size_t)e * D_MODEL + kb);
            wi[nt] = *reinterpret_cast<const s8*>(Wi + (size_t)(e + 128) * D_MODEL + kb);
            wo[nt] = *reinterpret_cast<const s8*>(Wi + (size_t)(e + 256) * D_MODEL + kb);
        }
        #pragma unroll
        for (int mt = 0; mt < 4; ++mt)
            #pragma unroll
            for (int nt = 0; nt < 2; ++nt) {
                aU[mt][nt] = __builtin_amdgcn_mfma_f32_16x16x32_bf16(xa[mt], wu[nt], aU[mt][nt], 0, 0, 0);
                aI[mt][nt] = __builtin_amdgcn_mfma_f32_16x16x32_bf16(xa[mt], wi[nt], aI[mt][nt], 0, 0, 0);
                aO[mt][nt] = __builtin_amdgcn_mfma_f32_16x16x32_bf16(xa[mt], wo[nt], aO[mt][nt], 0, 0, 0);
            }
    }

    #pragma unroll
    for (int mt = 0; mt < 4; ++mt)
        #pragma unroll
        for (int nt = 0; nt < 2; ++nt) {
            const int e = ch0 + nt * 16 + lrow;
            const size_t off = nbase + (size_t)e * HW + q0 + mt * 16 + grp * 4;
            us4 piu, pog;
            #pragma unroll
            for (int i = 0; i < 4; ++i) {
                piu[i] = f2b(sig_(aI[mt][nt][i]) * tanh_(aU[mt][nt][i]));
                pog[i] = f2b(sig_(aO[mt][nt][i]));
            }
            *reinterpret_cast<us4*>(iu + off) = piu;
            *reinterpret_cast<us4*>(og + off) = pog;
        }
}

// ---------------------------------------------------------------------------
// gates_f32: layer-0 spatial gates from fp32 tok. Stage X^T tile -> LDS, then
// 3-gate MFMA.
// ---------------------------------------------------------------------------
__global__ __launch_bounds__(256, 2) void gates_f32_kernel(
    const float* __restrict__ in, const ushort* __restrict__ Wi,
    ushort* __restrict__ iu, ushort* __restrict__ og)
{
    __shared__ ushort Xs[64][136];
    const int n   = blockIdx.x >> 4;
    const int q0  = (blockIdx.x & 15) << 6;
    const int tid = threadIdx.x;
    const size_t nbase = (size_t)n * (D_MODEL * HW);

    {
        const float* inb = in + nbase + q0;
        const int q   = tid & 63;
        const int dh0 = tid >> 6;
        for (int it = 0; it < 4; ++it) {
            const int dh = dh0 + it * 4;
            s8 pk;
            #pragma unroll
            for (int j = 0; j < 8; ++j)
                pk[j] = (short)f2b(inb[(size_t)(dh * 8 + j) * HW + q]);
            *reinterpret_cast<s8*>(&Xs[q][dh * 8]) = pk;
        }
    }
    __syncthreads();
    gates_from_lds(Xs, Wi, iu, og, nbase, q0, tid);
}

// ---------------------------------------------------------------------------
// fusedA: xs = Wo @ (og*S*scale) computed per-tile, kept in LDS (never hits
// global), immediately consumed by temporal gates GEMM (Wi2).
// In-place safe over S/og (tile fully staged first).
// ---------------------------------------------------------------------------
__global__ __launch_bounds__(256, 2) void fusedA_kernel(
    const ushort* __restrict__ S, const ushort* __restrict__ og_in,
    const ushort* __restrict__ Wo, const ushort* __restrict__ Wi2,
    ushort* __restrict__ iu, ushort* __restrict__ og, float scale)
{
    __shared__ ushort Gs[64][136];
    const int n   = blockIdx.x >> 4;
    const int q0  = (blockIdx.x & 15) << 6;
    const int tid = threadIdx.x;
    const size_t nbase = (size_t)n * (D_MODEL * HW);

    {   // stage gated product G[q][d]
        const ushort* Sb = S     + nbase + q0;
        const ushort* Ob = og_in + nbase + q0;
        const int q   = tid & 63;
        const int dh0 = tid >> 6;
        for (int it = 0; it < 4; ++it) {
            const int dh = dh0 + it * 4;
            s8 pk;
            #pragma unroll
            for (int j = 0; j < 8; ++j) {
                const size_t o = (size_t)(dh * 8 + j) * HW + q;
                pk[j] = (short)f2b(b2f(Ob[o]) * b2f(Sb[o]) * scale);
            }
            *reinterpret_cast<s8*>(&Gs[q][dh * 8]) = pk;
        }
    }
    __syncthreads();

    const int lane = tid & 63;
    const int wv   = tid >> 6;
    const int grp  = lane >> 4;
    const int lrow = lane & 15;
    const int ch0  = wv * 32;

    // MFMA1 orientation W: C rows = e (4 consecutive per lane) -> us4 LDS write
    f4 c1[2][4];
    #pragma unroll
    for (int et = 0; et < 2; ++et)
        #pragma unroll
        for (int qt = 0; qt < 4; ++qt) c1[et][qt] = (f4)0.f;

    #pragma unroll
    for (int kk = 0; kk < 4; ++kk) {
        const int kb = kk * 32 + grp * 8;
        s8 wf[2], xg[4];
        #pragma unroll
        for (int et = 0; et < 2; ++et)
            wf[et] = *reinterpret_cast<const s8*>(Wo + (size_t)(ch0 + et * 16 + lrow) * D_MODEL + kb);
        #pragma unroll
        for (int qt = 0; qt < 4; ++qt)
            xg[qt] = *reinterpret_cast<const s8*>(&Gs[qt * 16 + lrow][kb]);
        #pragma unroll
        for (int et = 0; et < 2; ++et)
            #pragma unroll
            for (int qt = 0; qt < 4; ++qt)
                c1[et][qt] = __builtin_amdgcn_mfma_f32_16x16x32_bf16(wf[et], xg[qt], c1[et][qt], 0, 0, 0);
    }
    __syncthreads();   // all Gs reads done

    // write xs tile into Gs as [q][e]
    #pragma unroll
    for (int et = 0; et < 2; ++et)
        #pragma unroll
        for (int qt = 0; qt < 4; ++qt) {
            const int q = qt * 16 + lrow;
            us4 pk;
            #pragma unroll
            for (int i = 0; i < 4; ++i) pk[i] = f2b(c1[et][qt][i]);
            *reinterpret_cast<us4*>(&Gs[q][ch0 + et * 16 + grp * 4]) = pk;
        }
    __syncthreads();

    gates_from_lds(Gs, Wi2, iu, og, nbase, q0, tid);
}

// ---------------------------------------------------------------------------
// fusedB: X = resid + Wo @ (og*S); optionally feed X straight into next
// layer's spatial gates GEMM (Wi2). f4 residual loads / X stores.
// ---------------------------------------------------------------------------
template <bool GATES>
__global__ __launch_bounds__(256, 2) void fusedB_kernel(
    const ushort* __restrict__ S, const ushort* __restrict__ og_in,
    const ushort* __restrict__ Wo, const float* __restrict__ resid,
    float* __restrict__ X, const ushort* __restrict__ Wi2,
    ushort* __restrict__ iu, ushort* __restrict__ og)
{
    __shared__ ushort Gs[64][136];
    const int n   = blockIdx.x >> 4;
    const int q0  = (blockIdx.x & 15) << 6;
    const int tid = threadIdx.x;
    const size_t nbase = (size_t)n * (D_MODEL * HW);

    {
        const ushort* Sb = S     + nbase + q0;
        const ushort* Ob = og_in + nbase + q0;
        const int q   = tid & 63;
        const int dh0 = tid >> 6;
        for (int it = 0; it < 4; ++it) {
            const int dh = dh0 + it * 4;
            s8 pk;
            #pragma unroll
            for (int j = 0; j < 8; ++j) {
                const size_t o = (size_t)(dh * 8 + j) * HW + q;
                pk[j] = (short)f2b(b2f(Ob[o]) * b2f(Sb[o]));
            }
            *reinterpret_cast<s8*>(&Gs[q][dh * 8]) = pk;
        }
    }
    __syncthreads();

    const int lane = tid & 63;
    const int wv   = tid >> 6;
    const int grp  = lane >> 4;
    const int lrow = lane & 15;
    const int ch0  = wv * 32;

    // MFMA1 orientation X: C rows = q -> f4 global stores
    f4 c1[4][2];
    #pragma unroll
    for (int mt = 0; mt < 4; ++mt)
        #pragma unroll
        for (int nt = 0; nt < 2; ++nt) c1[mt][nt] = (f4)0.f;

    #pragma unroll
    for (int kk = 0; kk < 4; ++kk) {
        const int kb = kk * 32 + grp * 8;
        s8 xg[4], wf[2];
        #pragma unroll
        for (int mt = 0; mt < 4; ++mt)
            xg[mt] = *reinterpret_cast<const s8*>(&Gs[mt * 16 + lrow][kb]);
        #pragma unroll
        for (int nt = 0; nt < 2; ++nt)
            wf[nt] = *reinterpret_cast<const s8*>(Wo + (size_t)(ch0 + nt * 16 + lrow) * D_MODEL + kb);
        #pragma unroll
        for (int mt = 0; mt < 4; ++mt)
            #pragma unroll
            for (int nt = 0; nt < 2; ++nt)
                c1[mt][nt] = __builtin_amdgcn_mfma_f32_16x16x32_bf16(xg[mt], wf[nt], c1[mt][nt], 0, 0, 0);
    }
    __syncthreads();   // all Gs reads done before overwrite

    #pragma unroll
    for (int mt = 0; mt < 4; ++mt)
        #pragma unroll
        for (int nt = 0; nt < 2; ++nt) {
            const int e    = ch0 + nt * 16 + lrow;
            const int qloc = mt * 16 + grp * 4;
            const size_t off = nbase + (size_t)e * HW + q0 + qloc;
            f4 r = *reinterpret_cast<const f4*>(resid + off);
            f4 v;
            #pragma unroll
            for (int i = 0; i < 4; ++i) v[i] = c1[mt][nt][i] + r[i];
            *reinterpret_cast<f4*>(X + off) = v;
            if constexpr (GATES) {
                #pragma unroll
                for (int i = 0; i < 4; ++i) Gs[qloc + i][e] = f2b(v[i]);
            }
        }

    if constexpr (GATES) {
        __syncthreads();
        gates_from_lds(Gs, Wi2, iu, og, nbase, q0, tid);
    }
}

// ---------------------------------------------------------------------------
// scan2d: per (n,d) 32x32 plane, sum of 4 directional scans, in place (bf16).
// ---------------------------------------------------------------------------
__global__ __launch_bounds__(128) void scan2d_kernel(
    ushort* __restrict__ buf, const float* __restrict__ Avec)
{
    __shared__ float L[4][32][33];
    __shared__ float S[4][32][33];
    const int pl = threadIdx.x >> 5;
    const int r  = threadIdx.x & 31;
    const int plane = blockIdx.x * 4 + pl;
    const int d = plane & (D_MODEL - 1);
    ushort* base = buf + (size_t)plane * HW;
    const float a = fminf(__expf(Avec[d]), 0.999f);

    for (int k = 0; k < 32; ++k) L[pl][k][r] = b2f(base[k * 32 + r]);
    __syncthreads();

    {
        float acc[32];
        float s = 0.f;
        #pragma unroll
        for (int j = 0; j < 32; ++j) { s = fmaf(a, s, L[pl][r][j]); acc[j] = s; }
        s = 0.f;
        #pragma unroll
        for (int j = 31; j >= 0; --j) { s = fmaf(a, s, L[pl][r][j]); acc[j] += s; }
        #pragma unroll
        for (int j = 0; j < 32; ++j) S[pl][r][j] = acc[j];
    }
    __syncthreads();
    {
        float s = 0.f;
        #pragma unroll
        for (int i = 0; i < 32; ++i) { s = fmaf(a, s, L[pl][i][r]); S[pl][i][r] += s; }
        s = 0.f;
        #pragma unroll
        for (int i = 31; i >= 0; --i) { s = fmaf(a, s, L[pl][i][r]); S[pl][i][r] += s; }
    }
    __syncthreads();
    for (int k = 0; k < 32; ++k) base[k * 32 + r] = f2b(S[pl][k][r]);
}

// ---------------------------------------------------------------------------
// tscan: causal scan over T in place (bf16), 2 q per thread (us2 loads).
// ---------------------------------------------------------------------------
__global__ __launch_bounds__(256) void tscan_kernel(
    ushort* __restrict__ buf, const float* __restrict__ Avec)
{
    const int idx = blockIdx.x * 256 + threadIdx.x;   // < 524288
    const int qh = idx & 511;
    const int d  = (idx >> 9) & 127;
    const int b  = idx >> 16;
    const float a = fminf(__expf(Avec[d]), 0.999f);
    size_t base = (size_t)b * (T_ * D_MODEL * HW) + (size_t)d * HW + qh * 2;
    float s0 = 0.f, s1 = 0.f;
    for (int t = 0; t < T_; ++t) {
        ushort* p = buf + base + (size_t)t * (D_MODEL * HW);
        us2 v = *reinterpret_cast<us2*>(p);
        s0 = fmaf(a, s0, b2f(v[0]));
        s1 = fmaf(a, s1, b2f(v[1]));
        us2 w; w[0] = f2b(s0); w[1] = f2b(s1);
        *reinterpret_cast<us2*>(p) = w;
    }
}

// ---------------------------------------------------------------------------
// ln: LayerNorm over D per position, two-pass, in place on X (fp32).
// ---------------------------------------------------------------------------
__global__ __launch_bounds__(256) void ln_kernel(
    float* __restrict__ X, const float* __restrict__ g, const float* __restrict__ b)
{
    const int p = blockIdx.x * 256 + threadIdx.x;
    if (p >= NIMG * HW) return;
    const int q = p & (HW - 1);
    const int n = p >> 10;
    const size_t base = (size_t)n * (D_MODEL * HW) + q;
    float sum = 0.f, sumsq = 0.f;
    for (int d = 0; d < D_MODEL; ++d) {
        const float x = X[base + (size_t)d * HW];
        sum += x; sumsq += x * x;
    }
    const float mean = sum * (1.f / D_MODEL);
    const float var  = sumsq * (1.f / D_MODEL) - mean * mean;
    const float rstd = rsqrtf(var + LN_EPSF);
    for (int d = 0; d < D_MODEL; ++d) {
        const size_t idx = base + (size_t)d * HW;
        X[idx] = (X[idx] - mean) * rstd * g[d] + b[d];
    }
}

// ---------------------------------------------------------------------------
extern "C" void kernel_launch(void* const* d_in, const int* in_sizes, int n_in,
                              void* d_out, int out_size, void* d_ws, size_t ws_size,
                              hipStream_t stream) {
    const float* tok   = (const float*)d_in[0];
    const float* s_inp = (const float*)d_in[1];
    const float* s_A   = (const float*)d_in[2];
    const float* s_out = (const float*)d_in[3];
    const float* t_inp = (const float*)d_in[4];
    const float* t_A   = (const float*)d_in[5];
    const float* t_out = (const float*)d_in[6];
    const float* ln_g  = (const float*)d_in[7];
    const float* ln_b  = (const float*)d_in[8];

    float*  X    = (float*)d_out;                    // residual stream fp32
    ushort* Abuf = (ushort*)d_ws;                    // 32MB bf16 (iu / S)
    ushort* Bbuf = Abuf + (size_t)16777216;          // 32MB bf16 (og)
    ushort* Wbf  = Bbuf + (size_t)16777216;          // ~1MB bf16 weights
    ushort* sWiB = Wbf;                              // 4*49152
    ushort* sWoB = Wbf + 196608;                     // 4*16384
    ushort* tWiB = Wbf + 262144;
    ushort* tWoB = Wbf + 458752;

    const dim3 blk256(256), blk128(128);

    wconv_kernel<<<768, blk256, 0, stream>>>(s_inp, sWiB, 196608);
    wconv_kernel<<<256, blk256, 0, stream>>>(s_out, sWoB, 65536);
    wconv_kernel<<<768, blk256, 0, stream>>>(t_inp, tWiB, 196608);
    wconv_kernel<<<256, blk256, 0, stream>>>(t_out, tWoB, 65536);

    // layer-0 spatial gates from tok
    gates_f32_kernel<<<2048, blk256, 0, stream>>>(tok, sWiB, Abuf, Bbuf);

    for (int l = 0; l < DEPTH; ++l) {
        const float* xin = (l == 0) ? tok : X;

        scan2d_kernel<<<4096, blk128, 0, stream>>>(Abuf, s_A + (size_t)l * 128);
        fusedA_kernel<<<2048, blk256, 0, stream>>>(
            Abuf, Bbuf, sWoB + (size_t)l * 16384, tWiB + (size_t)l * 49152,
            Abuf, Bbuf, 0.25f);
        tscan_kernel<<<2048, blk256, 0, stream>>>(Abuf, t_A + (size_t)l * 128);

        if (l < DEPTH - 1) {
            fusedB_kernel<true><<<2048, blk256, 0, stream>>>(
                Abuf, Bbuf, tWoB + (size_t)l * 16384, xin, X,
                sWiB + (size_t)(l + 1) * 49152, Abuf, Bbuf);
        } else {
            fusedB_kernel<false><<<2048, blk256, 0, stream>>>(
                Abuf, Bbuf, tWoB + (size_t)l * 16384, xin, X,
                nullptr, nullptr, nullptr);
        }
    }
    ln_kernel<<<512, blk256, 0, stream>>>(X, ln_g, ln_b);
}